// Round 8
// baseline (92.689 us; speedup 1.0000x reference)
//
#include <hip/hip_runtime.h>

// Sliding-window min (STL Always_[16,64]):
//   out[t][b] = min_{j=15..63} xpad[t-j][b],   xpad[s<0] = 1e6
// R8: C_TILE=256 -> halo amp 1.19 (vs 1.75 R7 / 1.375 R3). Established facts:
//   - bytes-bound at ~4.2 TB/s pattern BW (time tracks hbm_bytes across R1-R7)
//   - lane width (4/8/16B), occupancy (17-42%), nt stores: all null/negative
//   - compiler streams the cascade: VGPR ~64 regardless of C_TILE
// Only reducible term left is halo re-read bytes.

#define T_DIM 8192
#define B_DIM 4096
#define C_TILE 256              // outputs per thread along T
#define ALEN (C_TILE + 48)      // inputs per thread (window width 49)
#define LARGE_VAL 1e6f

__global__ __launch_bounds__(256)
void Temporal_Operator_kernel(const float* __restrict__ x,
                              float* __restrict__ out) {
    const int b  = blockIdx.x * blockDim.x + threadIdx.x;   // column
    const int t0 = blockIdx.y * C_TILE;                     // output tile start
    const long base = (long)t0 - 63;                        // first input row

    // Load inputs (negative rows -> LARGE; wave-uniform predicate, y-tile 0).
    float arr[ALEN];
    #pragma unroll
    for (int i = 0; i < ALEN; ++i) {
        long s = base + i;
        arr[i] = (s >= 0) ? x[s * B_DIM + b] : LARGE_VAL;
    }

    // Log-doubling forward window mins, in place:
    // after pass k, arr[i] = min(x[i .. i+k-1]) over the valid range.
    #pragma unroll
    for (int i = 0; i < ALEN - 1; ++i)  arr[i] = fminf(arr[i], arr[i + 1]);   // w2
    #pragma unroll
    for (int i = 0; i < ALEN - 3; ++i)  arr[i] = fminf(arr[i], arr[i + 2]);   // w4
    #pragma unroll
    for (int i = 0; i < ALEN - 7; ++i)  arr[i] = fminf(arr[i], arr[i + 4]);   // w8
    #pragma unroll
    for (int i = 0; i < ALEN - 15; ++i) arr[i] = fminf(arr[i], arr[i + 8]);   // w16
    #pragma unroll
    for (int i = 0; i < ALEN - 31; ++i) arr[i] = fminf(arr[i], arr[i + 16]);  // w32

    // w49[c] = min(w32[c], w32[c+17]) covers [c, c+48]; stream past caches.
    #pragma unroll
    for (int c = 0; c < C_TILE; ++c) {
        __builtin_nontemporal_store(fminf(arr[c], arr[c + 17]),
                                    &out[(long)(t0 + c) * B_DIM + b]);
    }
}

extern "C" void kernel_launch(void* const* d_in, const int* in_sizes, int n_in,
                              void* d_out, int out_size, void* d_ws, size_t ws_size,
                              hipStream_t stream) {
    const float* x = (const float*)d_in[0];
    float* out = (float*)d_out;

    dim3 block(256, 1, 1);
    dim3 grid(B_DIM / 256, T_DIM / C_TILE, 1);   // 16 x 32 blocks
    Temporal_Operator_kernel<<<grid, block, 0, stream>>>(x, out);
}

// Round 9
// 56.019 us; speedup vs baseline: 1.6546x; 1.6546x over previous
//
#include <hip/hip_runtime.h>

// Sliding-window min (STL Always_[16,64]):
//   out[t][b] = min_{j=15..63} xpad[t-j][b],   xpad[s<0] = 1e6
// R9: LDS-transposed WIDE STORES. Evidence R1-R8: time pins at ~56us wherever
// write=134MB (write stream ~2.4 TB/s), regardless of read bytes (76-161MB),
// width, occupancy (17-42%), nt. Copy ubench writes ~3.15 TB/s with 1KB/wave
// stores; ours are 256B/wave. Per-lane packing can't widen the wave footprint
// (cascade forces 1 col/thread; float4 ownership = VGPR 216, R6/R8 cliff).
// Fix: keep scalar cascade, transpose outputs through a 16x256 LDS tile, each
// wave stores full 1KB rows as float4. Loads unchanged from R7 (C_TILE=64).

#define T_DIM 8192
#define B_DIM 4096
#define C_TILE 64               // outputs per thread along T
#define ALEN (C_TILE + 48)      // inputs per thread (window width 49)
#define RCHUNK 16               // rows per LDS store chunk
#define NCHUNK (C_TILE / RCHUNK)
#define LARGE_VAL 1e6f

typedef float f32x4 __attribute__((ext_vector_type(4)));

__global__ __launch_bounds__(256)
void Temporal_Operator_kernel(const float* __restrict__ x,
                              float* __restrict__ out) {
    __shared__ float lds[RCHUNK][256];                      // 16 KiB

    const int tid = threadIdx.x;
    const int b0  = blockIdx.x * 256;                       // block's column base
    const int b   = b0 + tid;                               // this thread's column
    const int t0  = blockIdx.y * C_TILE;                    // output tile start
    const long base = (long)t0 - 63;                        // first input row

    // Load inputs (negative rows -> LARGE; wave-uniform predicate, y-tile 0).
    float arr[ALEN];
    #pragma unroll
    for (int i = 0; i < ALEN; ++i) {
        long s = base + i;
        arr[i] = (s >= 0) ? x[s * B_DIM + b] : LARGE_VAL;
    }

    // Log-doubling forward window mins, in place:
    // after pass k, arr[i] = min(x[i .. i+k-1]) over the valid range.
    #pragma unroll
    for (int i = 0; i < ALEN - 1; ++i)  arr[i] = fminf(arr[i], arr[i + 1]);   // w2
    #pragma unroll
    for (int i = 0; i < ALEN - 3; ++i)  arr[i] = fminf(arr[i], arr[i + 2]);   // w4
    #pragma unroll
    for (int i = 0; i < ALEN - 7; ++i)  arr[i] = fminf(arr[i], arr[i + 4]);   // w8
    #pragma unroll
    for (int i = 0; i < ALEN - 15; ++i) arr[i] = fminf(arr[i], arr[i + 8]);   // w16
    #pragma unroll
    for (int i = 0; i < ALEN - 31; ++i) arr[i] = fminf(arr[i], arr[i + 16]);  // w32

    // Store: w49[c] = min(w32[c], w32[c+17]). Transpose 16-row chunks through
    // LDS so each wave writes a full 1KB row (float4/lane, nt).
    const int lane = tid & 63;
    const int wv   = tid >> 6;
    #pragma unroll
    for (int k = 0; k < NCHUNK; ++k) {
        #pragma unroll
        for (int r = 0; r < RCHUNK; ++r) {
            int c = k * RCHUNK + r;
            lds[r][tid] = fminf(arr[c], arr[c + 17]);       // conflict-free
        }
        __syncthreads();
        #pragma unroll
        for (int j = 0; j < 4; ++j) {
            int r = wv + 4 * j;                             // one row per wave-instr
            f32x4 v = *(const f32x4*)&lds[r][lane * 4];     // canonical b128 read
            long t = (long)(t0 + k * RCHUNK + r);
            __builtin_nontemporal_store(v, (f32x4*)&out[t * B_DIM + b0 + lane * 4]);
        }
        __syncthreads();
    }
}

extern "C" void kernel_launch(void* const* d_in, const int* in_sizes, int n_in,
                              void* d_out, int out_size, void* d_ws, size_t ws_size,
                              hipStream_t stream) {
    const float* x = (const float*)d_in[0];
    float* out = (float*)d_out;

    dim3 block(256, 1, 1);
    dim3 grid(B_DIM / 256, T_DIM / C_TILE, 1);   // 16 x 128 blocks
    Temporal_Operator_kernel<<<grid, block, 0, stream>>>(x, out);
}